// Round 2
// baseline (68901.904 us; speedup 1.0000x reference)
//
#include <hip/hip_runtime.h>
#include <hip/hip_fp16.h>
#include <stdint.h>

#define B_  32
#define T_  2000
#define H_  512
#define NH_ 100
#define NM_ 65

typedef _Float16 f16x8 __attribute__((ext_vector_type(8)));
typedef _Float16 f16x2 __attribute__((ext_vector_type(2)));
typedef float    f32x4 __attribute__((ext_vector_type(4)));

typedef __attribute__((address_space(3))) void lds_void_t;
typedef __attribute__((address_space(1))) void glb_void_t;

__device__ __forceinline__ void gload_lds16(const void* g, void* l) {
  __builtin_amdgcn_global_load_lds((const glb_void_t*)g, (lds_void_t*)l, 16, 0, 0);
}

__device__ __forceinline__ float sigmoidf_(float x) {
  float e = __builtin_amdgcn_exp2f(-x * 1.44269504f);
  return __builtin_amdgcn_rcpf(1.0f + e);
}
__device__ __forceinline__ float tanhf_(float x) {
  float e = __builtin_amdgcn_exp2f(x * 2.88539008f);
  return 1.0f - 2.0f * __builtin_amdgcn_rcpf(e + 1.0f);
}
__device__ __forceinline__ float dot2(unsigned w, unsigned h, float acc) {
  return __builtin_amdgcn_fdot2(__builtin_bit_cast(f16x2, w),
                                __builtin_bit_cast(f16x2, h), acc, false);
}
__device__ __forceinline__ unsigned pack2(float a, float b) {
  __half2 h = __floats2half2_rn(a, b);
  return __builtin_bit_cast(unsigned, h);
}

// ---------------- hypernetwork ----------------
__global__ void hyper1(const float* __restrict__ es, const float* __restrict__ W1,
                       const float* __restrict__ b1, float* __restrict__ hE) {
  int b = blockIdx.x, o = threadIdx.x;   // 32 x 256
  float a = b1[o];
  #pragma unroll
  for (int c = 0; c < 16; ++c) a += es[b*16 + c] * W1[o*16 + c];
  hE[b*256 + o] = fmaxf(a, 0.f);
}

__global__ void hyper2(const float* __restrict__ hE,
                       const float* __restrict__ Wbh, const float* __restrict__ bbh,
                       const float* __restrict__ harmb,
                       const float* __restrict__ Wbn, const float* __restrict__ bbn,
                       const float* __restrict__ noiseb, float* __restrict__ effb) {
  int b = blockIdx.x, o = threadIdx.x;
  if (o < NH_) {
    float a = bbh[o] + harmb[o];
    for (int c = 0; c < 256; ++c) a += hE[b*256 + c] * Wbh[o*256 + c];
    effb[b*256 + o] = a;
  } else if (o < NH_ + NM_) {
    int q = o - NH_;
    float a = bbn[q] + noiseb[q];
    for (int c = 0; c < 256; ++c) a += hE[b*256 + c] * Wbn[q*256 + c];
    effb[b*256 + o] = a;
  }
}

// effW[b][o_base+o][h] = baseW[o*512+h] + bd[row] + sum_c Wd[row][c]*hE[b][c]
__global__ __launch_bounds__(256) void hyper3(
    const float* __restrict__ hE, const float* __restrict__ Wd,
    const float* __restrict__ bd, const float* __restrict__ baseW,
    __half* __restrict__ effW, int o_base) {
  __shared__ float wl[256*33];
  __shared__ float hEl[32*256];
  int tid = threadIdx.x;
  int row0 = blockIdx.x * 256;
  #pragma unroll
  for (int i = 0; i < 32; ++i) hEl[i*256 + tid] = hE[i*256 + tid];
  float acc[32];
  #pragma unroll
  for (int b = 0; b < 32; ++b) acc[b] = 0.f;
  for (int cc = 0; cc < 256; cc += 32) {
    __syncthreads();
    #pragma unroll
    for (int i = 0; i < 32; ++i) {
      int idx = i*256 + tid;
      int r = idx >> 5, c = idx & 31;
      wl[r*33 + c] = Wd[(size_t)(row0 + r)*256 + cc + c];
    }
    __syncthreads();
    #pragma unroll
    for (int c = 0; c < 32; ++c) {
      float w = wl[tid*33 + c];
      #pragma unroll
      for (int b = 0; b < 32; ++b) acc[b] += w * hEl[b*256 + cc + c];
    }
  }
  int row = row0 + tid;
  int o = row >> 9, h = row & 511;
  float base = baseW[row] + bd[row];
  #pragma unroll
  for (int b = 0; b < 32; ++b) {
    effW[((size_t)b*256 + o_base + o)*512 + h] = (__half)(acc[b] + base);
  }
}

// ---------------- converts ----------------
__global__ void cvt_f16(const float* __restrict__ in, __half* __restrict__ out, int n) {
  int i = blockIdx.x*256 + threadIdx.x;
  if (i < n) out[i] = (__half)in[i];
}

// Wp4[q][t], q = r*32+jj (r=gate-row block, jj=k-quad), t = hf*512+u
__global__ void pack_whh(const float* __restrict__ Whh, uint4* __restrict__ Wp4) {
  int idx = blockIdx.x*256 + threadIdx.x;    // 96*1024
  int q = idx >> 10, t = idx & 1023;
  int r = q >> 5, jj = q & 31;
  int u = t & 511, hf = t >> 9;
  int row = u + r*512;
  int k0 = hf*256 + jj*8;
  const float* src = Whh + (size_t)row*512 + k0;
  uint4 out;
  out.x = pack2(src[0], src[1]);
  out.y = pack2(src[2], src[3]);
  out.z = pack2(src[4], src[5]);
  out.w = pack2(src[6], src[7]);
  Wp4[idx] = out;
}

// ---------------- pre layer (per chunk) ----------------
__global__ void pre_kernel(const float* __restrict__ f0, const float* __restrict__ loud,
                           const float* __restrict__ preW, const float* __restrict__ preb,
                           __half* __restrict__ xpre, int CH, int c0) {
  int b = blockIdx.y;
  int idx = blockIdx.x*256 + threadIdx.x;    // CH*512
  int t = idx >> 9, h = idx & 511;
  int mg = b*T_ + c0 + t;
  float v = f0[mg]*preW[h*2+0] + loud[mg]*preW[h*2+1] + preb[h];
  v = v >= 0.f ? v : 0.01f*v;
  xpre[((size_t)b*CH + t)*512 + h] = (__half)v;
}

// ---------------- trunk GEMM (NT, K=512, 128x128 tile, f16 MFMA) ----------------
// A [M][512], B [N][512], C [M][N] f16 (+bias, ACT: 0 none, 1 leaky)
template<int ACT>
__global__ __launch_bounds__(256) void gemm_nt(
    const __half* __restrict__ A, const __half* __restrict__ B,
    __half* __restrict__ C, const float* __restrict__ bias, int N) {
  constexpr int K = 512;
  __shared__ __align__(16) __half As[128*64];
  __shared__ __align__(16) __half Bs[128*64];
  int tid = threadIdx.x;
  int bx = blockIdx.x, by = blockIdx.y;
  const __half* Ab = A + (size_t)bx*128*K;
  const __half* Bb = B + (size_t)by*128*K;
  f32x4 acc[4][4] = {};
  int lane = tid & 63;
  int wv = tid >> 6, wr = wv >> 1, wc = wv & 1;
  int lr = lane & 15, lk = lane >> 4;

  for (int kt = 0; kt < K/64; ++kt) {
    #pragma unroll
    for (int j = 0; j < 4; ++j) {
      int idx = j*256 + tid;
      int row = idx >> 3, seg = idx & 7;
      const __half* gpA = Ab + (size_t)row*K + kt*64 + seg*8;
      const __half* gpB = Bb + (size_t)row*K + kt*64 + seg*8;
      __half* lpA = As + (size_t)(j*256 + (tid & ~63))*8;
      __half* lpB = Bs + (size_t)(j*256 + (tid & ~63))*8;
      gload_lds16(gpA, lpA);
      gload_lds16(gpB, lpB);
    }
    __syncthreads();
    #pragma unroll
    for (int ks = 0; ks < 2; ++ks) {
      f16x8 af[4], bf[4];
      #pragma unroll
      for (int i = 0; i < 4; ++i)
        af[i] = *(const f16x8*)(As + (wr*64 + i*16 + lr)*64 + ks*32 + lk*8);
      #pragma unroll
      for (int j2 = 0; j2 < 4; ++j2)
        bf[j2] = *(const f16x8*)(Bs + (wc*64 + j2*16 + lr)*64 + ks*32 + lk*8);
      #pragma unroll
      for (int i = 0; i < 4; ++i)
        #pragma unroll
        for (int j2 = 0; j2 < 4; ++j2)
          acc[i][j2] = __builtin_amdgcn_mfma_f32_16x16x32_f16(af[i], bf[j2], acc[i][j2], 0, 0, 0);
    }
    __syncthreads();
  }

  #pragma unroll
  for (int j2 = 0; j2 < 4; ++j2) {
    int col = by*128 + wc*64 + j2*16 + lr;
    float bv = bias[col];
    #pragma unroll
    for (int i = 0; i < 4; ++i) {
      int row0 = bx*128 + wr*64 + i*16 + lk*4;
      #pragma unroll
      for (int r = 0; r < 4; ++r) {
        float v = acc[i][j2][r] + bv;
        if (ACT == 1) v = v >= 0.f ? v : 0.01f*v;
        C[(size_t)(row0 + r)*N + col] = (__half)v;
      }
    }
  }
}

// ---------------- heads GEMM: per-batch modulated weights, sigmoid, fp32 out ----------------
__global__ __launch_bounds__(256) void heads_gemm(
    const __half* __restrict__ Apc, const __half* __restrict__ effW,
    const float* __restrict__ effb, float* __restrict__ out, int CH, int c0) {
  constexpr int K = 512;
  __shared__ __align__(16) __half As[128*64];
  __shared__ __align__(16) __half Bs[128*64];
  int tid = threadIdx.x;
  int bx = blockIdx.x, by = blockIdx.y, b = blockIdx.z;
  const __half* Ab = Apc + (size_t)b*CH*K;
  const __half* Bb = effW + ((size_t)b*256 + (size_t)by*128)*K;
  f32x4 acc[4][4] = {};
  int lane = tid & 63;
  int wv = tid >> 6, wr = wv >> 1, wc = wv & 1;
  int lr = lane & 15, lk = lane >> 4;

  for (int kt = 0; kt < K/64; ++kt) {
    #pragma unroll
    for (int j = 0; j < 4; ++j) {
      int idx = j*256 + tid;
      int row = idx >> 3, seg = idx & 7;
      int ar = bx*128 + row; if (ar > CH-1) ar = CH-1;   // clamp (dup reads, masked stores)
      const __half* gpA = Ab + (size_t)ar*K + kt*64 + seg*8;
      const __half* gpB = Bb + (size_t)row*K + kt*64 + seg*8;
      __half* lpA = As + (size_t)(j*256 + (tid & ~63))*8;
      __half* lpB = Bs + (size_t)(j*256 + (tid & ~63))*8;
      gload_lds16(gpA, lpA);
      gload_lds16(gpB, lpB);
    }
    __syncthreads();
    #pragma unroll
    for (int ks = 0; ks < 2; ++ks) {
      f16x8 af[4], bf[4];
      #pragma unroll
      for (int i = 0; i < 4; ++i)
        af[i] = *(const f16x8*)(As + (wr*64 + i*16 + lr)*64 + ks*32 + lk*8);
      #pragma unroll
      for (int j2 = 0; j2 < 4; ++j2)
        bf[j2] = *(const f16x8*)(Bs + (wc*64 + j2*16 + lr)*64 + ks*32 + lk*8);
      #pragma unroll
      for (int i = 0; i < 4; ++i)
        #pragma unroll
        for (int j2 = 0; j2 < 4; ++j2)
          acc[i][j2] = __builtin_amdgcn_mfma_f32_16x16x32_f16(af[i], bf[j2], acc[i][j2], 0, 0, 0);
    }
    __syncthreads();
  }

  #pragma unroll
  for (int j2 = 0; j2 < 4; ++j2) {
    int o = by*128 + wc*64 + j2*16 + lr;
    if (o < NH_ + NM_) {
      float bv = effb[b*256 + o];
      #pragma unroll
      for (int i = 0; i < 4; ++i) {
        #pragma unroll
        for (int r = 0; r < 4; ++r) {
          int trow = bx*128 + wr*64 + i*16 + lk*4 + r;
          if (trow < CH) {
            int tg = c0 + trow;
            float v = sigmoidf_(acc[i][j2][r] + bv);
            if (o < NH_)
              out[((size_t)b*T_ + tg)*NH_ + o] = v;
            else
              out[(size_t)B_*T_*NH_ + ((size_t)b*T_ + tg)*NM_ + (o - NH_)] = v;
          }
        }
      }
    }
  }
}

// ---------------- GRU scan (chunked): 32 WGs x 1024 threads, W_hh in VGPRs ----------------
__global__ __launch_bounds__(1024) void gru_scan(
    const uint4* __restrict__ Wp4, const __half* __restrict__ gi_c,
    const float* __restrict__ bhh, __half* __restrict__ ys_c,
    float* __restrict__ hstate, int CH, int first) {
  int b = blockIdx.x;
  int t = threadIdx.x;
  int u = t & 511;
  int hf = t >> 9;

  __shared__ __align__(16) unsigned hp[256];   // packed f16x2 hidden state (512 halfs)
  __shared__ float part[512*3];

  uint4 wq[96];
  #pragma unroll
  for (int q = 0; q < 96; ++q) wq[q] = Wp4[q*1024 + t];

  float bh0 = bhh[u], bh1 = bhh[u + 512], bh2 = bhh[u + 1024];
  float hreg = 0.f;
  if (!hf) {
    hreg = first ? 0.f : hstate[b*512 + u];
    ((__half*)hp)[u] = (__half)hreg;
  }
  __syncthreads();

  const __half* gib = gi_c + (size_t)b*CH*1536;
  __half* ysb = ys_c + (size_t)b*CH*512;
  const uint4* hp4 = (const uint4*)hp;

  for (int s = 0; s < CH; ++s) {
    float gir = 0.f, giz = 0.f, gin = 0.f;
    if (hf == 0) {
      const __half* g = gib + (size_t)s*1536 + u;
      gir = (float)g[0]; giz = (float)g[512]; gin = (float)g[1024];
    }
    float a0 = 0.f, a1 = 0.f, a2 = 0.f;
    #pragma unroll
    for (int jj = 0; jj < 32; ++jj) {
      uint4 hv = hp4[(hf << 5) + jj];
      a0 = dot2(wq[jj].x, hv.x, a0);  a0 = dot2(wq[jj].y, hv.y, a0);
      a0 = dot2(wq[jj].z, hv.z, a0);  a0 = dot2(wq[jj].w, hv.w, a0);
      a1 = dot2(wq[32+jj].x, hv.x, a1); a1 = dot2(wq[32+jj].y, hv.y, a1);
      a1 = dot2(wq[32+jj].z, hv.z, a1); a1 = dot2(wq[32+jj].w, hv.w, a1);
      a2 = dot2(wq[64+jj].x, hv.x, a2); a2 = dot2(wq[64+jj].y, hv.y, a2);
      a2 = dot2(wq[64+jj].z, hv.z, a2); a2 = dot2(wq[64+jj].w, hv.w, a2);
    }
    if (hf) { part[u*3+0] = a0; part[u*3+1] = a1; part[u*3+2] = a2; }
    __syncthreads();
    if (!hf) {
      float ghr = a0 + part[u*3+0] + bh0;
      float ghz = a1 + part[u*3+1] + bh1;
      float ghn = a2 + part[u*3+2] + bh2;
      float r = sigmoidf_(gir + ghr);
      float z = sigmoidf_(giz + ghz);
      float n = tanhf_(gin + r*ghn);
      hreg = (1.f - z)*n + z*hreg;
      ysb[(size_t)s*512 + u] = (__half)hreg;
      ((__half*)hp)[u] = (__half)hreg;
    }
    __syncthreads();
  }
  if (!hf) hstate[b*512 + u] = hreg;
}

// ---------------- launch ----------------
extern "C" void kernel_launch(void* const* d_in, const int* in_sizes, int n_in,
                              void* d_out, int out_size, void* d_ws, size_t ws_size,
                              hipStream_t stream) {
  const float* f0     = (const float*)d_in[0];
  const float* loud   = (const float*)d_in[1];
  const float* es     = (const float*)d_in[2];
  const float* preW   = (const float*)d_in[3];
  const float* preb   = (const float*)d_in[4];
  const float* Wih    = (const float*)d_in[5];
  const float* Whh    = (const float*)d_in[6];
  const float* b_ih   = (const float*)d_in[7];
  const float* b_hh   = (const float*)d_in[8];
  const float* postW  = (const float*)d_in[9];
  const float* postb  = (const float*)d_in[10];
  const float* harmW  = (const float*)d_in[11];
  const float* harmb  = (const float*)d_in[12];
  const float* noiseW = (const float*)d_in[13];
  const float* noiseb = (const float*)d_in[14];
  const float* hypW1  = (const float*)d_in[15];
  const float* hypb1  = (const float*)d_in[16];
  const float* Wdh    = (const float*)d_in[17];
  const float* bdh    = (const float*)d_in[18];
  const float* Wbh    = (const float*)d_in[19];
  const float* bbh    = (const float*)d_in[20];
  const float* Wdn    = (const float*)d_in[21];
  const float* bdn    = (const float*)d_in[22];
  const float* Wbn    = (const float*)d_in[23];
  const float* bbn    = (const float*)d_in[24];
  (void)in_sizes; (void)n_in; (void)out_size;

  // ---- workspace layout (chunked; CH picked to fit ws_size) ----
  const size_t FIXED = 12288ull*1024ull;   // ~12 MB fixed region (aligned sum below)
  int CH = 20;
  {
    const int opts[5] = {400, 200, 100, 40, 20};
    for (int i = 0; i < 5; ++i) {
      size_t need = FIXED + (size_t)opts[i] * 163840ull + 65536ull;
      if (need <= ws_size) { CH = opts[i]; break; }
    }
  }
  const int NC = T_ / CH;
  const int Mc = B_ * CH;

  char* w = (char*)d_ws;
  size_t off = 0;
  auto alloc = [&](size_t bytes) -> void* {
    void* p = (void*)(w + off);
    off += (bytes + 255) & ~(size_t)255;
    return p;
  };
  float*  hE      = (float*)alloc((size_t)32*256*4);
  float*  effb    = (float*)alloc((size_t)32*256*4);
  float*  hstate  = (float*)alloc((size_t)32*512*4);
  __half* effW    = (__half*)alloc((size_t)32*256*512*2);
  __half* Wih16   = (__half*)alloc((size_t)1536*512*2);
  __half* postW16 = (__half*)alloc((size_t)512*512*2);
  uint4*  Wp4     = (uint4*)alloc((size_t)96*1024*16);
  __half* xpre    = (__half*)alloc((size_t)Mc*512*2);   // aliased: post GEMM output
  __half* gibuf   = (__half*)alloc((size_t)Mc*1536*2);
  __half* ysbuf   = (__half*)alloc((size_t)Mc*512*2);
  __half* postc   = xpre;   // xpre dead after gi GEMM

  // ---- prologue (weights, hypernet) ----
  hyper1<<<32, 256, 0, stream>>>(es, hypW1, hypb1, hE);
  hyper2<<<32, 256, 0, stream>>>(hE, Wbh, bbh, harmb, Wbn, bbn, noiseb, effb);
  hyper3<<<200, 256, 0, stream>>>(hE, Wdh, bdh, harmW, effW, 0);
  hyper3<<<130, 256, 0, stream>>>(hE, Wdn, bdn, noiseW, effW, NH_);
  cvt_f16<<<(1536*512)/256, 256, 0, stream>>>(Wih, Wih16, 1536*512);
  cvt_f16<<<(512*512)/256, 256, 0, stream>>>(postW, postW16, 512*512);
  pack_whh<<<384, 256, 0, stream>>>(Whh, Wp4);

  // ---- chunked trunk ----
  for (int c = 0; c < NC; ++c) {
    int c0 = c * CH;
    pre_kernel<<<dim3(CH*2, 32), 256, 0, stream>>>(f0, loud, preW, preb, xpre, CH, c0);
    gemm_nt<0><<<dim3(Mc/128, 12), 256, 0, stream>>>(xpre, Wih16, gibuf, b_ih, 1536);
    gru_scan<<<32, 1024, 0, stream>>>(Wp4, gibuf, b_hh, ysbuf, hstate, CH, c == 0 ? 1 : 0);
    gemm_nt<1><<<dim3(Mc/128, 4), 256, 0, stream>>>(ysbuf, postW16, postc, postb, 512);
    heads_gemm<<<dim3((CH+127)/128, 2, 32), 256, 0, stream>>>(postc, effW, effb,
                                                              (float*)d_out, CH, c0);
  }
}

// Round 3
// 68517.029 us; speedup vs baseline: 1.0056x; 1.0056x over previous
//
#include <hip/hip_runtime.h>
#include <hip/hip_fp16.h>
#include <stdint.h>

#define B_  32
#define T_  2000
#define H_  512
#define NH_ 100
#define NM_ 65

typedef _Float16 f16x8 __attribute__((ext_vector_type(8)));
typedef _Float16 f16x2 __attribute__((ext_vector_type(2)));
typedef float    f32x4 __attribute__((ext_vector_type(4)));

typedef __attribute__((address_space(3))) void lds_void_t;
typedef __attribute__((address_space(1))) void glb_void_t;

__device__ __forceinline__ void gload_lds16(const void* g, void* l) {
  __builtin_amdgcn_global_load_lds((const glb_void_t*)g, (lds_void_t*)l, 16, 0, 0);
}

__device__ __forceinline__ float sigmoidf_(float x) {
  float e = __builtin_amdgcn_exp2f(-x * 1.44269504f);
  return __builtin_amdgcn_rcpf(1.0f + e);
}
__device__ __forceinline__ float tanhf_(float x) {
  float e = __builtin_amdgcn_exp2f(x * 2.88539008f);
  return 1.0f - 2.0f * __builtin_amdgcn_rcpf(e + 1.0f);
}
__device__ __forceinline__ float dot2(unsigned w, unsigned h, float acc) {
  return __builtin_amdgcn_fdot2(__builtin_bit_cast(f16x2, w),
                                __builtin_bit_cast(f16x2, h), acc, false);
}
__device__ __forceinline__ unsigned pack2(float a, float b) {
  __half2 h = __floats2half2_rn(a, b);
  return __builtin_bit_cast(unsigned, h);
}

// ---------------- hypernetwork ----------------
__global__ void hyper1(const float* __restrict__ es, const float* __restrict__ W1,
                       const float* __restrict__ b1, float* __restrict__ hE) {
  int b = blockIdx.x, o = threadIdx.x;   // 32 x 256
  float a = b1[o];
  #pragma unroll
  for (int c = 0; c < 16; ++c) a += es[b*16 + c] * W1[o*16 + c];
  hE[b*256 + o] = fmaxf(a, 0.f);
}

__global__ void hyper2(const float* __restrict__ hE,
                       const float* __restrict__ Wbh, const float* __restrict__ bbh,
                       const float* __restrict__ harmb,
                       const float* __restrict__ Wbn, const float* __restrict__ bbn,
                       const float* __restrict__ noiseb, float* __restrict__ effb) {
  int b = blockIdx.x, o = threadIdx.x;
  if (o < NH_) {
    float a = bbh[o] + harmb[o];
    for (int c = 0; c < 256; ++c) a += hE[b*256 + c] * Wbh[o*256 + c];
    effb[b*256 + o] = a;
  } else if (o < NH_ + NM_) {
    int q = o - NH_;
    float a = bbn[q] + noiseb[q];
    for (int c = 0; c < 256; ++c) a += hE[b*256 + c] * Wbn[q*256 + c];
    effb[b*256 + o] = a;
  }
}

// effW[b][o_base+o][h] = baseW[o*512+h] + bd[row] + sum_c Wd[row][c]*hE[b][c]
__global__ __launch_bounds__(256) void hyper3(
    const float* __restrict__ hE, const float* __restrict__ Wd,
    const float* __restrict__ bd, const float* __restrict__ baseW,
    __half* __restrict__ effW, int o_base) {
  __shared__ float wl[256*33];
  __shared__ float hEl[32*256];
  int tid = threadIdx.x;
  int row0 = blockIdx.x * 256;
  #pragma unroll
  for (int i = 0; i < 32; ++i) hEl[i*256 + tid] = hE[i*256 + tid];
  float acc[32];
  #pragma unroll
  for (int b = 0; b < 32; ++b) acc[b] = 0.f;
  for (int cc = 0; cc < 256; cc += 32) {
    __syncthreads();
    #pragma unroll
    for (int i = 0; i < 32; ++i) {
      int idx = i*256 + tid;
      int r = idx >> 5, c = idx & 31;
      wl[r*33 + c] = Wd[(size_t)(row0 + r)*256 + cc + c];
    }
    __syncthreads();
    #pragma unroll
    for (int c = 0; c < 32; ++c) {
      float w = wl[tid*33 + c];
      #pragma unroll
      for (int b = 0; b < 32; ++b) acc[b] += w * hEl[b*256 + cc + c];
    }
  }
  int row = row0 + tid;
  int o = row >> 9, h = row & 511;
  float base = baseW[row] + bd[row];
  #pragma unroll
  for (int b = 0; b < 32; ++b) {
    effW[((size_t)b*256 + o_base + o)*512 + h] = (__half)(acc[b] + base);
  }
}

// ---------------- converts ----------------
__global__ void cvt_f16(const float* __restrict__ in, __half* __restrict__ out, int n) {
  int i = blockIdx.x*256 + threadIdx.x;
  if (i < n) out[i] = (__half)in[i];
}

// Wp4[q][t], q = r*32+jj (r=gate-row block, jj=k-quad), t = hf*512+u
__global__ void pack_whh(const float* __restrict__ Whh, uint4* __restrict__ Wp4) {
  int idx = blockIdx.x*256 + threadIdx.x;    // 96*1024
  int q = idx >> 10, t = idx & 1023;
  int r = q >> 5, jj = q & 31;
  int u = t & 511, hf = t >> 9;
  int row = u + r*512;
  int k0 = hf*256 + jj*8;
  const float* src = Whh + (size_t)row*512 + k0;
  uint4 out;
  out.x = pack2(src[0], src[1]);
  out.y = pack2(src[2], src[3]);
  out.z = pack2(src[4], src[5]);
  out.w = pack2(src[6], src[7]);
  Wp4[idx] = out;
}

// ---------------- pre layer (per chunk) ----------------
__global__ void pre_kernel(const float* __restrict__ f0, const float* __restrict__ loud,
                           const float* __restrict__ preW, const float* __restrict__ preb,
                           __half* __restrict__ xpre, int CH, int c0) {
  int b = blockIdx.y;
  int idx = blockIdx.x*256 + threadIdx.x;    // CH*512
  int t = idx >> 9, h = idx & 511;
  int mg = b*T_ + c0 + t;
  float v = f0[mg]*preW[h*2+0] + loud[mg]*preW[h*2+1] + preb[h];
  v = v >= 0.f ? v : 0.01f*v;
  xpre[((size_t)b*CH + t)*512 + h] = (__half)v;
}

// ---------------- trunk GEMM (NT, K=512, 128x128 tile, f16 MFMA) ----------------
// A [M][512], B [N][512], C [M][N] f16 (+bias, ACT: 0 none, 1 leaky)
template<int ACT>
__global__ __launch_bounds__(256) void gemm_nt(
    const __half* __restrict__ A, const __half* __restrict__ B,
    __half* __restrict__ C, const float* __restrict__ bias, int N) {
  constexpr int K = 512;
  __shared__ __align__(16) __half As[128*64];
  __shared__ __align__(16) __half Bs[128*64];
  int tid = threadIdx.x;
  int bx = blockIdx.x, by = blockIdx.y;
  const __half* Ab = A + (size_t)bx*128*K;
  const __half* Bb = B + (size_t)by*128*K;
  f32x4 acc[4][4] = {};
  int lane = tid & 63;
  int wv = tid >> 6, wr = wv >> 1, wc = wv & 1;
  int lr = lane & 15, lk = lane >> 4;

  for (int kt = 0; kt < K/64; ++kt) {
    #pragma unroll
    for (int j = 0; j < 4; ++j) {
      int idx = j*256 + tid;
      int row = idx >> 3, seg = idx & 7;
      const __half* gpA = Ab + (size_t)row*K + kt*64 + seg*8;
      const __half* gpB = Bb + (size_t)row*K + kt*64 + seg*8;
      __half* lpA = As + (size_t)(j*256 + (tid & ~63))*8;
      __half* lpB = Bs + (size_t)(j*256 + (tid & ~63))*8;
      gload_lds16(gpA, lpA);
      gload_lds16(gpB, lpB);
    }
    __syncthreads();
    #pragma unroll
    for (int ks = 0; ks < 2; ++ks) {
      f16x8 af[4], bf[4];
      #pragma unroll
      for (int i = 0; i < 4; ++i)
        af[i] = *(const f16x8*)(As + (wr*64 + i*16 + lr)*64 + ks*32 + lk*8);
      #pragma unroll
      for (int j2 = 0; j2 < 4; ++j2)
        bf[j2] = *(const f16x8*)(Bs + (wc*64 + j2*16 + lr)*64 + ks*32 + lk*8);
      #pragma unroll
      for (int i = 0; i < 4; ++i)
        #pragma unroll
        for (int j2 = 0; j2 < 4; ++j2)
          acc[i][j2] = __builtin_amdgcn_mfma_f32_16x16x32_f16(af[i], bf[j2], acc[i][j2], 0, 0, 0);
    }
    __syncthreads();
  }

  #pragma unroll
  for (int j2 = 0; j2 < 4; ++j2) {
    int col = by*128 + wc*64 + j2*16 + lr;
    float bv = bias[col];
    #pragma unroll
    for (int i = 0; i < 4; ++i) {
      int row0 = bx*128 + wr*64 + i*16 + lk*4;
      #pragma unroll
      for (int r = 0; r < 4; ++r) {
        float v = acc[i][j2][r] + bv;
        if (ACT == 1) v = v >= 0.f ? v : 0.01f*v;
        C[(size_t)(row0 + r)*N + col] = (__half)v;
      }
    }
  }
}

// ---------------- heads GEMM: per-batch modulated weights, sigmoid, fp32 out ----------------
__global__ __launch_bounds__(256) void heads_gemm(
    const __half* __restrict__ Apc, const __half* __restrict__ effW,
    const float* __restrict__ effb, float* __restrict__ out, int CH, int c0) {
  constexpr int K = 512;
  __shared__ __align__(16) __half As[128*64];
  __shared__ __align__(16) __half Bs[128*64];
  int tid = threadIdx.x;
  int bx = blockIdx.x, by = blockIdx.y, b = blockIdx.z;
  const __half* Ab = Apc + (size_t)b*CH*K;
  const __half* Bb = effW + ((size_t)b*256 + (size_t)by*128)*K;
  f32x4 acc[4][4] = {};
  int lane = tid & 63;
  int wv = tid >> 6, wr = wv >> 1, wc = wv & 1;
  int lr = lane & 15, lk = lane >> 4;

  for (int kt = 0; kt < K/64; ++kt) {
    #pragma unroll
    for (int j = 0; j < 4; ++j) {
      int idx = j*256 + tid;
      int row = idx >> 3, seg = idx & 7;
      int ar = bx*128 + row; if (ar > CH-1) ar = CH-1;   // clamp (dup reads, masked stores)
      const __half* gpA = Ab + (size_t)ar*K + kt*64 + seg*8;
      const __half* gpB = Bb + (size_t)row*K + kt*64 + seg*8;
      __half* lpA = As + (size_t)(j*256 + (tid & ~63))*8;
      __half* lpB = Bs + (size_t)(j*256 + (tid & ~63))*8;
      gload_lds16(gpA, lpA);
      gload_lds16(gpB, lpB);
    }
    __syncthreads();
    #pragma unroll
    for (int ks = 0; ks < 2; ++ks) {
      f16x8 af[4], bf[4];
      #pragma unroll
      for (int i = 0; i < 4; ++i)
        af[i] = *(const f16x8*)(As + (wr*64 + i*16 + lr)*64 + ks*32 + lk*8);
      #pragma unroll
      for (int j2 = 0; j2 < 4; ++j2)
        bf[j2] = *(const f16x8*)(Bs + (wc*64 + j2*16 + lr)*64 + ks*32 + lk*8);
      #pragma unroll
      for (int i = 0; i < 4; ++i)
        #pragma unroll
        for (int j2 = 0; j2 < 4; ++j2)
          acc[i][j2] = __builtin_amdgcn_mfma_f32_16x16x32_f16(af[i], bf[j2], acc[i][j2], 0, 0, 0);
    }
    __syncthreads();
  }

  #pragma unroll
  for (int j2 = 0; j2 < 4; ++j2) {
    int o = by*128 + wc*64 + j2*16 + lr;
    if (o < NH_ + NM_) {
      float bv = effb[b*256 + o];
      #pragma unroll
      for (int i = 0; i < 4; ++i) {
        #pragma unroll
        for (int r = 0; r < 4; ++r) {
          int trow = bx*128 + wr*64 + i*16 + lk*4 + r;
          if (trow < CH) {
            int tg = c0 + trow;
            float v = sigmoidf_(acc[i][j2][r] + bv);
            if (o < NH_)
              out[((size_t)b*T_ + tg)*NH_ + o] = v;
            else
              out[(size_t)B_*T_*NH_ + ((size_t)b*T_ + tg)*NM_ + (o - NH_)] = v;
          }
        }
      }
    }
  }
}

// ---------------- GRU scan (chunked): 32 WGs x 1024 threads, W_hh in VGPRs ----------------
// amdgpu_waves_per_eu(4,4): pin 4 waves/SIMD (1 WG/CU) -> VGPR budget 512/wave so the
// 3x32 uint4 (384-VGPR) weight arrays stay register-resident (round-2 spilled at the
// default occupancy target: VGPR_Count=64, 6.9 GB scratch traffic/dispatch).
__global__ __launch_bounds__(1024) __attribute__((amdgpu_waves_per_eu(4, 4)))
void gru_scan(
    const uint4* __restrict__ Wp4, const __half* __restrict__ gi_c,
    const float* __restrict__ bhh, __half* __restrict__ ys_c,
    float* __restrict__ hstate, int CH, int first) {
  int b = blockIdx.x;
  int t = threadIdx.x;
  int u = t & 511;
  int hf = t >> 9;

  __shared__ __align__(16) unsigned hp[256];   // packed f16x2 hidden state (512 halfs)
  __shared__ float part[512*3];

  uint4 wq0[32], wq1[32], wq2[32];
  #pragma unroll
  for (int j = 0; j < 32; ++j) wq0[j] = Wp4[(size_t)j*1024 + t];
  #pragma unroll
  for (int j = 0; j < 32; ++j) wq1[j] = Wp4[(size_t)(32 + j)*1024 + t];
  #pragma unroll
  for (int j = 0; j < 32; ++j) wq2[j] = Wp4[(size_t)(64 + j)*1024 + t];

  float bh0 = bhh[u], bh1 = bhh[u + 512], bh2 = bhh[u + 1024];
  float hreg = 0.f;
  if (!hf) {
    hreg = first ? 0.f : hstate[b*512 + u];
    ((__half*)hp)[u] = (__half)hreg;
  }
  __syncthreads();

  const __half* gib = gi_c + (size_t)b*CH*1536;
  __half* ysb = ys_c + (size_t)b*CH*512;
  const uint4* hp4 = (const uint4*)hp;

  for (int s = 0; s < CH; ++s) {
    // gi loads issue here; consumed ~3000 cycles later (after the dot loop) -> latency hidden
    float gir = 0.f, giz = 0.f, gin = 0.f;
    if (hf == 0) {
      const __half* g = gib + (size_t)s*1536 + u;
      gir = (float)g[0]; giz = (float)g[512]; gin = (float)g[1024];
    }
    float a0 = 0.f, a1 = 0.f, a2 = 0.f;
    #pragma unroll
    for (int jj = 0; jj < 32; ++jj) {
      uint4 hv = hp4[(hf << 5) + jj];   // wave-uniform -> LDS broadcast, conflict-free
      a0 = dot2(wq0[jj].x, hv.x, a0);  a0 = dot2(wq0[jj].y, hv.y, a0);
      a0 = dot2(wq0[jj].z, hv.z, a0);  a0 = dot2(wq0[jj].w, hv.w, a0);
      a1 = dot2(wq1[jj].x, hv.x, a1);  a1 = dot2(wq1[jj].y, hv.y, a1);
      a1 = dot2(wq1[jj].z, hv.z, a1);  a1 = dot2(wq1[jj].w, hv.w, a1);
      a2 = dot2(wq2[jj].x, hv.x, a2);  a2 = dot2(wq2[jj].y, hv.y, a2);
      a2 = dot2(wq2[jj].z, hv.z, a2);  a2 = dot2(wq2[jj].w, hv.w, a2);
    }
    if (hf) { part[u*3+0] = a0; part[u*3+1] = a1; part[u*3+2] = a2; }
    __syncthreads();
    if (!hf) {
      float ghr = a0 + part[u*3+0] + bh0;
      float ghz = a1 + part[u*3+1] + bh1;
      float ghn = a2 + part[u*3+2] + bh2;
      float r = sigmoidf_(gir + ghr);
      float z = sigmoidf_(giz + ghz);
      float n = tanhf_(gin + r*ghn);
      hreg = (1.f - z)*n + z*hreg;
      ysb[(size_t)s*512 + u] = (__half)hreg;
      ((__half*)hp)[u] = (__half)hreg;
    }
    __syncthreads();
  }
  if (!hf) hstate[b*512 + u] = hreg;
}

// ---------------- launch ----------------
extern "C" void kernel_launch(void* const* d_in, const int* in_sizes, int n_in,
                              void* d_out, int out_size, void* d_ws, size_t ws_size,
                              hipStream_t stream) {
  const float* f0     = (const float*)d_in[0];
  const float* loud   = (const float*)d_in[1];
  const float* es     = (const float*)d_in[2];
  const float* preW   = (const float*)d_in[3];
  const float* preb   = (const float*)d_in[4];
  const float* Wih    = (const float*)d_in[5];
  const float* Whh    = (const float*)d_in[6];
  const float* b_ih   = (const float*)d_in[7];
  const float* b_hh   = (const float*)d_in[8];
  const float* postW  = (const float*)d_in[9];
  const float* postb  = (const float*)d_in[10];
  const float* harmW  = (const float*)d_in[11];
  const float* harmb  = (const float*)d_in[12];
  const float* noiseW = (const float*)d_in[13];
  const float* noiseb = (const float*)d_in[14];
  const float* hypW1  = (const float*)d_in[15];
  const float* hypb1  = (const float*)d_in[16];
  const float* Wdh    = (const float*)d_in[17];
  const float* bdh    = (const float*)d_in[18];
  const float* Wbh    = (const float*)d_in[19];
  const float* bbh    = (const float*)d_in[20];
  const float* Wdn    = (const float*)d_in[21];
  const float* bdn    = (const float*)d_in[22];
  const float* Wbn    = (const float*)d_in[23];
  const float* bbn    = (const float*)d_in[24];
  (void)in_sizes; (void)n_in; (void)out_size;

  // ---- workspace layout (chunked; CH picked to fit ws_size) ----
  const size_t FIXED = 12288ull*1024ull;   // ~12 MB fixed region
  int CH = 20;
  {
    const int opts[8] = {2000, 1000, 500, 400, 200, 100, 40, 20};
    for (int i = 0; i < 8; ++i) {
      size_t need = FIXED + (size_t)opts[i] * 163840ull + 65536ull;
      if (need <= ws_size) { CH = opts[i]; break; }
    }
  }
  const int NC = T_ / CH;
  const int Mc = B_ * CH;

  char* w = (char*)d_ws;
  size_t off = 0;
  auto alloc = [&](size_t bytes) -> void* {
    void* p = (void*)(w + off);
    off += (bytes + 255) & ~(size_t)255;
    return p;
  };
  float*  hE      = (float*)alloc((size_t)32*256*4);
  float*  effb    = (float*)alloc((size_t)32*256*4);
  float*  hstate  = (float*)alloc((size_t)32*512*4);
  __half* effW    = (__half*)alloc((size_t)32*256*512*2);
  __half* Wih16   = (__half*)alloc((size_t)1536*512*2);
  __half* postW16 = (__half*)alloc((size_t)512*512*2);
  uint4*  Wp4     = (uint4*)alloc((size_t)96*1024*16);
  __half* xpre    = (__half*)alloc((size_t)Mc*512*2);   // aliased: post GEMM output
  __half* gibuf   = (__half*)alloc((size_t)Mc*1536*2);
  __half* ysbuf   = (__half*)alloc((size_t)Mc*512*2);
  __half* postc   = xpre;   // xpre dead after gi GEMM

  // ---- prologue (weights, hypernet) ----
  hyper1<<<32, 256, 0, stream>>>(es, hypW1, hypb1, hE);
  hyper2<<<32, 256, 0, stream>>>(hE, Wbh, bbh, harmb, Wbn, bbn, noiseb, effb);
  hyper3<<<200, 256, 0, stream>>>(hE, Wdh, bdh, harmW, effW, 0);
  hyper3<<<130, 256, 0, stream>>>(hE, Wdn, bdn, noiseW, effW, NH_);
  cvt_f16<<<(1536*512)/256, 256, 0, stream>>>(Wih, Wih16, 1536*512);
  cvt_f16<<<(512*512)/256, 256, 0, stream>>>(postW, postW16, 512*512);
  pack_whh<<<384, 256, 0, stream>>>(Whh, Wp4);

  // ---- chunked trunk ----
  for (int c = 0; c < NC; ++c) {
    int c0 = c * CH;
    pre_kernel<<<dim3(CH*2, 32), 256, 0, stream>>>(f0, loud, preW, preb, xpre, CH, c0);
    gemm_nt<0><<<dim3(Mc/128, 12), 256, 0, stream>>>(xpre, Wih16, gibuf, b_ih, 1536);
    gru_scan<<<32, 1024, 0, stream>>>(Wp4, gibuf, b_hh, ysbuf, hstate, CH, c == 0 ? 1 : 0);
    gemm_nt<1><<<dim3(Mc/128, 4), 256, 0, stream>>>(ysbuf, postW16, postc, postb, 512);
    heads_gemm<<<dim3((CH+127)/128, 2, 32), 256, 0, stream>>>(postc, effW, effb,
                                                              (float*)d_out, CH, c0);
  }
}